// Round 1
// baseline (37.005 us; speedup 1.0000x reference)
//
#include <hip/hip_runtime.h>

// ClusterLoss closed form:
//   F  = sum(W^2)                (omega_mean)
//   t_d = sum_i W[d,i]           (row sums; t = n * w_bar)
//   omega_between + omega_within = F - ||t||^2 / n   (S_b cancels, weights equal)
//   out = F + 0.5*(F - ||t||^2/n)/batch_size
// group_ids never needed.

#define D_ROWS 1024
#define N_CLS  50000
#define NVEC   (N_CLS / 4)   // 12500 float4 per row

__global__ __launch_bounds__(256) void cluster_row_reduce(
    const float* __restrict__ W,
    float* __restrict__ row_sum,
    float* __restrict__ row_sq)
{
    const int row = blockIdx.x;
    const float4* __restrict__ Wrow =
        reinterpret_cast<const float4*>(W + (size_t)row * N_CLS);

    float s = 0.0f, q = 0.0f;
    for (int i = threadIdx.x; i < NVEC; i += 256) {
        float4 v = Wrow[i];
        s += v.x + v.y + v.z + v.w;
        q += v.x * v.x + v.y * v.y + v.z * v.z + v.w * v.w;
    }

    // wave64 butterfly reduce
    #pragma unroll
    for (int off = 32; off > 0; off >>= 1) {
        s += __shfl_down(s, off, 64);
        q += __shfl_down(q, off, 64);
    }

    __shared__ float ss[4], sq[4];
    const int wid  = threadIdx.x >> 6;
    const int lane = threadIdx.x & 63;
    if (lane == 0) { ss[wid] = s; sq[wid] = q; }
    __syncthreads();
    if (threadIdx.x == 0) {
        row_sum[row] = ss[0] + ss[1] + ss[2] + ss[3];
        row_sq[row]  = sq[0] + sq[1] + sq[2] + sq[3];
    }
}

__global__ __launch_bounds__(256) void cluster_final_reduce(
    const float* __restrict__ row_sum,
    const float* __restrict__ row_sq,
    const int* __restrict__ bs_ptr,
    float* __restrict__ out)
{
    float t2 = 0.0f, f = 0.0f;
    for (int i = threadIdx.x; i < D_ROWS; i += 256) {
        float rs = row_sum[i];
        t2 += rs * rs;
        f  += row_sq[i];
    }

    #pragma unroll
    for (int off = 32; off > 0; off >>= 1) {
        t2 += __shfl_down(t2, off, 64);
        f  += __shfl_down(f, off, 64);
    }

    __shared__ float st[4], sf[4];
    const int wid  = threadIdx.x >> 6;
    const int lane = threadIdx.x & 63;
    if (lane == 0) { st[wid] = t2; sf[wid] = f; }
    __syncthreads();
    if (threadIdx.x == 0) {
        float T2 = st[0] + st[1] + st[2] + st[3];
        float F  = sf[0] + sf[1] + sf[2] + sf[3];
        float bs = (float)bs_ptr[0];
        out[0] = F + 0.5f * (F - T2 / (float)N_CLS) / bs;
    }
}

extern "C" void kernel_launch(void* const* d_in, const int* in_sizes, int n_in,
                              void* d_out, int out_size, void* d_ws, size_t ws_size,
                              hipStream_t stream) {
    const float* W      = (const float*)d_in[0];
    // d_in[1] = group_ids : unused (loss is invariant to grouping — see header)
    const int*   bs_ptr = (const int*)d_in[2];
    float*       out    = (float*)d_out;

    float* row_sum = (float*)d_ws;            // D_ROWS floats
    float* row_sq  = row_sum + D_ROWS;        // D_ROWS floats

    cluster_row_reduce<<<D_ROWS, 256, 0, stream>>>(W, row_sum, row_sq);
    cluster_final_reduce<<<1, 256, 0, stream>>>(row_sum, row_sq, bs_ptr, out);
}